// Round 4
// baseline (31.319 us; speedup 1.0000x reference)
//
#include <hip/hip_runtime.h>
#include <stdint.h>

// Problem constants
constexpr int T = 2048;
constexpr int B = 8;
constexpr int C = 1024;
constexpr int H = 16;
constexpr int K = 31;
constexpr int BC = B * C;            // 8192, stride between time steps

// Tiling
constexpr int TT = 32;               // outputs per thread / time steps per block
constexpr int NR = K - 1 + TT;       // 62 LDS rows (window incl. halo)
constexpr int BLOCK = 256;
constexpr int BLK_PER_CHUNK = BC / BLOCK;    // 32
constexpr int NCHUNK = T / TT;               // 64
constexpr int NBLK = BLK_PER_CHUNK * NCHUNK; // 2048

typedef const __attribute__((address_space(1))) uint32_t gas_u32;
typedef __attribute__((address_space(3))) uint32_t las_u32;

// ---------------------------------------------------------------------------
// out[t,b,c] = sum_{d=0..K-1} wr[d] * x[t-d, b, c] + bias[c]
// Stage x tile into LDS via fire-and-forget global_load_lds (no reg chain),
// then FMA ladder from LDS with static register indices.
// ---------------------------------------------------------------------------
__global__ __launch_bounds__(BLOCK, 2) void lconv_tbc_kernel(
        const float* __restrict__ x,
        const float* __restrict__ w,
        const float* __restrict__ bias,
        float* __restrict__ out) {
    __shared__ float tile[NR][BLOCK];   // 62 KiB -> 2 blocks/CU

    const int tid = threadIdx.x;
    const int wid = tid >> 6;
    const int lane = tid & 63;
    const int cb = blockIdx.x & (BLK_PER_CHUNK - 1);   // bc slice
    const int chunk = blockIdx.x / BLK_PER_CHUNK;      // time chunk
    const int bc0 = cb * BLOCK;
    const int bc = bc0 + tid;
    const int c = bc & (C - 1);
    // Each 64-lane wave spans exactly one head (G=64, aligned):
    const int h = __builtin_amdgcn_readfirstlane(c >> 6);
    const int t0 = chunk * TT;

    // --- Stage [NR][256] tile: row r is global time t0-30+r. Wave w does rows
    // r = w, w+4, ... Each row = 256 floats = 64 lanes x 16B: dest is
    // wave-uniform base + lane*16 (the global_load_lds layout requirement).
    for (int r = wid; r < NR; r += 4) {
        const int tg = t0 - (K - 1) + r;
        if (tg >= 0) {
            const float* src = x + (size_t)tg * BC + bc0 + lane * 4;
            __builtin_amdgcn_global_load_lds(
                (gas_u32*)src, (las_u32*)&tile[r][lane * 4], 16, 0, 0);
        } else {
            // causal zero padding (only blocks with chunk==0)
            float4 z = {0.f, 0.f, 0.f, 0.f};
            *(float4*)&tile[r][lane * 4] = z;
        }
    }

    // --- Per-wave softmax of this head's taps (overlaps the DMA).
    float wv[K];
    float m = -1e30f;
    #pragma unroll
    for (int k = 0; k < K; ++k) {
        wv[k] = w[h * K + k];
        m = fmaxf(m, wv[k]);
    }
    float s = 0.0f;
    #pragma unroll
    for (int k = 0; k < K; ++k) {
        wv[k] = __expf(wv[k] - m);
        s += wv[k];
    }
    const float inv = 1.0f / s;
    // Reversed weights, forced wave-uniform -> SGPRs.
    float wr[K];
    #pragma unroll
    for (int d = 0; d < K; ++d)
        wr[d] = __uint_as_float(
            __builtin_amdgcn_readfirstlane(__float_as_uint(wv[K - 1 - d] * inv)));
    const float bi = bias[c];

    __syncthreads();   // drains vmcnt(0): whole tile resident

    // --- LDS -> registers: 62 ds_read_b32, lanes consecutive (2-way, free).
    float buf[NR];
    #pragma unroll
    for (int r = 0; r < NR; ++r) buf[r] = tile[r][tid];

    // --- 32 outputs x 31 FMAs, all register indices compile-time constant.
    const int base = t0 * BC + bc;   // element index fits in int (max 16.8M)
    #pragma unroll
    for (int u = 0; u < TT; ++u) {
        float acc = bi;
        #pragma unroll
        for (int d = 0; d < K; ++d)
            acc = fmaf(wr[d], buf[K - 1 + u - d], acc);
        __builtin_nontemporal_store(acc, &out[base + u * BC]);
    }
}

extern "C" void kernel_launch(void* const* d_in, const int* in_sizes, int n_in,
                              void* d_out, int out_size, void* d_ws, size_t ws_size,
                              hipStream_t stream) {
    const float* x = (const float*)d_in[0];      // [T, B, C]
    const float* w = (const float*)d_in[1];      // [H, 1, K]
    const float* bias = (const float*)d_in[2];   // [C]
    float* out = (float*)d_out;                  // [T, B, C]

    lconv_tbc_kernel<<<dim3(NBLK), dim3(BLOCK), 0, stream>>>(x, w, bias, out);
}